// Round 3
// baseline (220.998 us; speedup 1.0000x reference)
//
#include <hip/hip_runtime.h>

// Boundary_binaryLoss: 15x15 binary morphology boundary mask + masked NLL mean.
// B=32, C=2, H=480, W=864. logits [B,C,H,W] f32, labels [B,H,W] i32 in {0,1,255}.
//
// valid(b,h,w) = (label != 255) && (clipped 15x15 window has a px with
//   np_label==0 (label 0 or 255) AND a px with np_label==255 (label 1))
// loss = -sum(valid ? logits[b,label,h,w] : 0) / max(#valid, 1)
//
// R1: atomics -> per-block partials (180->66us).
// R2: register prefetch of logits silently sunk (VGPR=24 proved it). 66us.
// R3: global_load_lds staging: __syncthreads drains vmcnt(0) -> dead. 66us.
// R4: barrier-free 1-wave tiles, scalar loads. STILL 66us, VALU 27%, BW 20%,
//     bank-conflict 0. Lesson: R0/R3/R4 all issue ~78 narrow (4B/lane)
//     requests per wave consumed in ~8-load VGPR-limited waitcnt batches ->
//     ~10 serial queue-latency waits per wave. Duration is set by the request
//     stream, not bytes (data is even L3-resident: FETCH 102MB < inputs).
// R5: fat requests, few serial waits, no barriers:
//       - lane owns 4 cols; labels via 22x int4 (1KB/wave-request)
//       - logits via 16x float4 (8 rows x 2 channels), issued BEFORE the
//         shuffle/vertical phase so latency hides under morphology VALU
//       - horizontal 15-OR exact over 4-col lanes: per-lane prefix/suffix
//         ORs + 8 u64 shuffles; vertical 15-OR: u64 shift-OR doubling
//       - TH=8 row-chunk, 216-col strips (864 = 4*216, zero overlap),
//         7680 autonomous waves, tail-only __syncthreads for block reduce

namespace {
constexpr int B_ = 32;
constexpr int H_ = 480;
constexpr int W_ = 864;
constexpr int HW = H_ * W_;
constexpr int R_ = 7;
constexpr int TH_ = 8;                   // output rows per wave
constexpr int LH = TH_ + 2 * R_;         // 22 label rows read
constexpr int SW = 216;                  // output cols per strip
constexpr int NSX = W_ / SW;             // 4 (exact -> no overlap, no masks)
constexpr int NSY = H_ / TH_;            // 60
constexpr int WPB = 4;                   // waves per block
constexpr int NTILE = B_ * NSY * NSX;    // 7680 wave-tiles
constexpr int NBLKP = NTILE / WPB;       // 1920 blocks
} // namespace

__device__ __forceinline__ unsigned long long shfl_up64(unsigned long long x, int d) {
  return __shfl_up(x, d, 64);
}
__device__ __forceinline__ unsigned long long shfl_dn64(unsigned long long x, int d) {
  return __shfl_down(x, d, 64);
}

extern "C" __global__ __launch_bounds__(256, 4)
void boundary_loss_main(const float* __restrict__ logits,
                        const int* __restrict__ labels,
                        double2* __restrict__ partials)
{
  __shared__ double red_s[WPB];
  __shared__ unsigned red_c[WPB];

  const int tid = threadIdx.x;
  const int lane = tid & 63;
  const int wv = tid >> 6;
  const int t = blockIdx.x * WPB + wv;        // wave-tile id
  const int b = t / (NSY * NSX);
  const int rr = t - b * (NSY * NSX);
  const int sy = rr >> 2;                     // NSX == 4
  const int sx = rr & 3;

  const int gr0 = sy * TH_;                   // first output image row
  const int wb = sx * SW - 8;                 // window col base (lane 0, j 0)
  const int cb0 = wb + 4 * lane;              // this lane's 4-col base
  const bool colinb = (cb0 >= 0) && (cb0 + 3 < W_);   // W%4==0: all-or-none
  const int cbc = colinb ? cb0 : (cb0 < 0 ? 0 : W_ - 4);

  const int* __restrict__ lab = labels + b * HW + cbc;
  const float* __restrict__ lg = logits + (size_t)(2 * b) * HW;

  // ---- phase 1: 22 fat label loads (int4 = 4 cols/lane, 1KB/wave/req) ----
  int4 lv[LH];
#pragma unroll
  for (int a = 0; a < LH; ++a) {
    int gr = gr0 - R_ + a;
    gr = gr < 0 ? 0 : (gr >= H_ ? H_ - 1 : gr);   // clamped; masked below
    lv[a] = *(const int4*)(lab + gr * W_);
  }

  // ---- phase 2: pack flags. f[j]: 2 bits/row (bit0 np==0, bit1 np==255);
  //      c[j]: 2 bits/output-row (bit0 label==1, bit1 ignore) ----
  unsigned long long f0 = 0, f1 = 0, f2 = 0, f3 = 0;
  unsigned cp0 = 0, cp1 = 0, cp2 = 0, cp3 = 0;
#pragma unroll
  for (int a = 0; a < LH; ++a) {
    const int4 v = lv[a];
    const unsigned e1x = (v.x == 1), e1y = (v.y == 1),
                   e1z = (v.z == 1), e1w = (v.w == 1);
    // f 2-bit: label==1 -> 2 (has np255); else (0 or 255) -> 1 (has np0)
    f0 |= (unsigned long long)(1u + e1x) << (2 * a);
    f1 |= (unsigned long long)(1u + e1y) << (2 * a);
    f2 |= (unsigned long long)(1u + e1z) << (2 * a);
    f3 |= (unsigned long long)(1u + e1w) << (2 * a);
    if (a >= R_ && a < R_ + TH_) {
      const int sh = 2 * (a - R_);
      cp0 |= (e1x | ((unsigned)(v.x == 255) << 1)) << sh;
      cp1 |= (e1y | ((unsigned)(v.y == 255) << 1)) << sh;
      cp2 |= (e1z | ((unsigned)(v.z == 255) << 1)) << sh;
      cp3 |= (e1w | ((unsigned)(v.w == 255) << 1)) << sh;
    }
  }
  // clip: OOB image rows / OOB lane columns contribute nothing
  {
    const int tv = gr0 == 0 ? R_ : 0;                 // invalid top rows
    const int hi = LH < (487 - gr0) ? LH : (487 - gr0); // first invalid bottom
    unsigned long long rm = ((1ull << (2 * (hi - tv))) - 1ull) << (2 * tv);
    if (!colinb) rm = 0;
    f0 &= rm; f1 &= rm; f2 &= rm; f3 &= rm;
  }

  // ---- phase 3: issue ALL logits loads now (latency hides under phase 4) --
  const bool outl = (lane >= 2) && (lane < 56);       // 54 lanes x 4 = 216 cols
  float4 g0[TH_], g1[TH_];
  if (outl) {
    const float* pg = lg + (size_t)gr0 * W_ + cb0;
#pragma unroll
    for (int o = 0; o < TH_; ++o) {
      g0[o] = *(const float4*)(pg + o * W_);
      g1[o] = *(const float4*)(pg + o * W_ + HW);
    }
  }

  // ---- phase 4: horizontal 15-OR, exact per column over 4-col lanes ----
  // col 4l+j window [4l+j-7, 4l+j+7]:
  //  j=0: sfx3(l-2)|all(l-1)|all(l)|all(l+1)
  //  j=1: sfx2(l-2)|  core            |pfx1(l+2)
  //  j=2: sfx1(l-2)|  core            |pfx2(l+2)
  //  j=3:           all(l-1..l+1)     |pfx3(l+2)
  // shuffle garbage only reaches lanes outside [2,56) -> never consumed.
  const unsigned long long allf = f0 | f1 | f2 | f3;
  const unsigned long long s2 = f2 | f3, s3 = f1 | s2;
  const unsigned long long p2 = f0 | f1, p3 = p2 | f2;
  const unsigned long long core =
      shfl_up64(allf, 1) | allf | shfl_dn64(allf, 1);
  unsigned long long w0 = core | shfl_up64(s3, 2);
  unsigned long long w1 = core | shfl_up64(s2, 2) | shfl_dn64(f0, 2);
  unsigned long long w2 = core | shfl_up64(f3, 2) | shfl_dn64(p2, 2);
  unsigned long long w3 = core | shfl_dn64(p3, 2);

  // ---- phase 5: vertical 15-OR (bits 2o = OR over label rows o..o+14) ----
  w0 |= w0 >> 2;  w0 |= w0 >> 4;  w0 |= w0 >> 8;  w0 |= w0 >> 14;
  w1 |= w1 >> 2;  w1 |= w1 >> 4;  w1 |= w1 >> 8;  w1 |= w1 >> 14;
  w2 |= w2 >> 2;  w2 |= w2 >> 4;  w2 |= w2 >> 8;  w2 |= w2 >> 14;
  w3 |= w3 >> 2;  w3 |= w3 >> 4;  w3 |= w3 >> 8;  w3 |= w3 >> 14;

  // ---- phase 6: select + accumulate (consumes g as it arrives) ----
  double lsum = 0.0;
  unsigned lcnt = 0;
  if (outl) {
#pragma unroll
    for (int o = 0; o < TH_; ++o) {
      const unsigned b0 = (unsigned)(w0 >> (2 * o)) & 3u;
      const unsigned b1 = (unsigned)(w1 >> (2 * o)) & 3u;
      const unsigned b2 = (unsigned)(w2 >> (2 * o)) & 3u;
      const unsigned b3 = (unsigned)(w3 >> (2 * o)) & 3u;
      const unsigned q0 = (cp0 >> (2 * o)) & 3u;
      const unsigned q1 = (cp1 >> (2 * o)) & 3u;
      const unsigned q2 = (cp2 >> (2 * o)) & 3u;
      const unsigned q3 = (cp3 >> (2 * o)) & 3u;
      const float4 a = g0[o], c = g1[o];
      const bool k0 = (b0 == 3u) && !(q0 & 2u);
      const bool k1 = (b1 == 3u) && !(q1 & 2u);
      const bool k2 = (b2 == 3u) && !(q2 & 2u);
      const bool k3 = (b3 == 3u) && !(q3 & 2u);
      lsum += k0 ? (double)((q0 & 1u) ? c.x : a.x) : 0.0;
      lsum += k1 ? (double)((q1 & 1u) ? c.y : a.y) : 0.0;
      lsum += k2 ? (double)((q2 & 1u) ? c.z : a.z) : 0.0;
      lsum += k3 ? (double)((q3 & 1u) ? c.w : a.w) : 0.0;
      lcnt += (unsigned)k0 + k1 + k2 + k3;
    }
  }

  // ---- wave + block reduction -> one double2 per block ----
#pragma unroll
  for (int off = 32; off > 0; off >>= 1) {
    lsum += __shfl_down(lsum, off, 64);
    lcnt += __shfl_down(lcnt, off, 64);
  }
  if ((tid & 63) == 0) { red_s[wv] = lsum; red_c[wv] = lcnt; }
  __syncthreads();                            // tail-only
  if (tid == 0) {
    const double s = red_s[0] + red_s[1] + red_s[2] + red_s[3];
    const double c = (double)(red_c[0] + red_c[1] + red_c[2] + red_c[3]);
    partials[blockIdx.x] = make_double2(s, c);
  }
}

extern "C" __global__ __launch_bounds__(1024)
void boundary_loss_final(const double2* __restrict__ partials,
                         float* __restrict__ out)
{
  __shared__ double red_s[16];
  __shared__ double red_c[16];
  const int tid = threadIdx.x;
  double s = 0.0, c = 0.0;
  for (int i = tid; i < NBLKP; i += 1024) {
    const double2 p = partials[i];
    s += p.x;
    c += p.y;
  }
#pragma unroll
  for (int off = 32; off > 0; off >>= 1) {
    s += __shfl_down(s, off, 64);
    c += __shfl_down(c, off, 64);
  }
  const int wave = tid >> 6;
  if ((tid & 63) == 0) { red_s[wave] = s; red_c[wave] = c; }
  __syncthreads();
  if (tid == 0) {
    double ts = 0.0, tc = 0.0;
#pragma unroll
    for (int i = 0; i < 16; ++i) { ts += red_s[i]; tc += red_c[i]; }
    if (tc < 1.0) tc = 1.0;
    out[0] = (float)(-ts / tc);
  }
}

extern "C" void kernel_launch(void* const* d_in, const int* in_sizes, int n_in,
                              void* d_out, int out_size, void* d_ws, size_t ws_size,
                              hipStream_t stream)
{
  const float* logits = (const float*)d_in[0];
  const int* labels = (const int*)d_in[1];
  float* out = (float*)d_out;
  double2* partials = (double2*)d_ws;  // NBLKP*16 B = 30,720 B; every slot
                                       // written by main -> no init needed.

  boundary_loss_main<<<dim3(NBLKP), 256, 0, stream>>>(logits, labels, partials);
  boundary_loss_final<<<1, 1024, 0, stream>>>(partials, out);
}

// Round 4
// 191.905 us; speedup vs baseline: 1.1516x; 1.1516x over previous
//
#include <hip/hip_runtime.h>

// Boundary_binaryLoss: 15x15 binary morphology boundary mask + masked NLL mean.
// B=32, C=2, H=480, W=864. logits [B,C,H,W] f32, labels [B,H,W] i32 in {0,1,255}.
//
// valid(b,h,w) = (label != 255) && (clipped 15x15 window has a px with
//   np_label==0 (label 0 or 255) AND a px with np_label==255 (label 1))
// loss = -sum(valid ? logits[b,label,h,w] : 0) / max(#valid, 1)
//
// R1: atomics -> per-block partials (180->66us).
// R2: register prefetch of logits silently sunk (VGPR=24 proved it). 66us.
// R3: global_load_lds staging: __syncthreads drains vmcnt(0) -> dead. 66us.
// R4: barrier-free 1-wave tiles, scalar loads. 65us, VALU 27%, BW 20%.
//     Theory: ~10 SERIAL congested-latency waits per wave (VGPR=36 -> tiny
//     load batches); T_wave ~ 28us.
// R5: fat int4/float4 requests BUT load-all/fold-all arrays forced 88+64
//     regs live -> compiler capped VGPR=64 and SPILLED: WRITE_SIZE 67KB ->
//     130MB of scratch traffic, 91us. The fat-request idea was never tested.
// R6: same fat requests, spill-proof shape:
//       - FUSED label load+fold loop (22x int4): compiler software-pipelines
//         to its own register budget (issue ~8-16 ahead, fold behind vmcnt)
//         instead of holding 88 raw regs live
//       - 16x float4 logits issued before morphology (the one big live set,
//         64 VGPR), consumed after; ~2-3 serial waits/wave total vs ~10
//       - __launch_bounds__(256,2): VGPR cap 256, no heuristic spill
//     Falsifiable: WRITE_SIZE must collapse back to ~70KB; dur 91 -> 30-45us.

namespace {
constexpr int B_ = 32;
constexpr int H_ = 480;
constexpr int W_ = 864;
constexpr int HW = H_ * W_;
constexpr int R_ = 7;
constexpr int TH_ = 8;                   // output rows per wave
constexpr int LH = TH_ + 2 * R_;         // 22 label rows read
constexpr int SW = 216;                  // output cols per strip
constexpr int NSX = W_ / SW;             // 4 (exact -> no overlap)
constexpr int NSY = H_ / TH_;            // 60
constexpr int WPB = 4;                   // waves per block
constexpr int NTILE = B_ * NSY * NSX;    // 7680 wave-tiles
constexpr int NBLKP = NTILE / WPB;       // 1920 blocks
} // namespace

__device__ __forceinline__ unsigned long long shfl_up64(unsigned long long x, int d) {
  return __shfl_up(x, d, 64);
}
__device__ __forceinline__ unsigned long long shfl_dn64(unsigned long long x, int d) {
  return __shfl_down(x, d, 64);
}

extern "C" __global__ __launch_bounds__(256, 2)
void boundary_loss_main(const float* __restrict__ logits,
                        const int* __restrict__ labels,
                        double2* __restrict__ partials)
{
  __shared__ double red_s[WPB];
  __shared__ unsigned red_c[WPB];

  const int tid = threadIdx.x;
  const int lane = tid & 63;
  const int wv = tid >> 6;
  const int t = blockIdx.x * WPB + wv;        // wave-tile id
  const int b = t / (NSY * NSX);
  const int rr = t - b * (NSY * NSX);
  const int sy = rr >> 2;                     // NSX == 4
  const int sx = rr & 3;

  const int gr0 = sy * TH_;                   // first output image row
  const int wb = sx * SW - 8;                 // window col base (lane 0, j 0)
  const int cb0 = wb + 4 * lane;              // this lane's 4-col base
  const bool colinb = (cb0 >= 0) && (cb0 + 3 < W_);   // W%4==0: all-or-none
  const int cbc = colinb ? cb0 : (cb0 < 0 ? 0 : W_ - 4);

  const int* __restrict__ lab = labels + b * HW + cbc;
  const float* __restrict__ lg = logits + (size_t)(2 * b) * HW;

  // ---- phase 1: FUSED label load+fold. 22 independent int4 loads (1KB/wave
  //      requests); immediate consumption lets the compiler pipeline issue
  //      depth against its register budget instead of spilling. ----
  // f[j]: 2 bits per label row (bit0: np==0 i.e. label 0/255; bit1: np==255
  // i.e. label 1). c[j]: 2 bits per OUTPUT row (bit0: label==1, bit1: ignore)
  unsigned long long f0 = 0, f1 = 0, f2 = 0, f3 = 0;
  unsigned cp0 = 0, cp1 = 0, cp2 = 0, cp3 = 0;
#pragma unroll
  for (int a = 0; a < LH; ++a) {
    int gr = gr0 - R_ + a;
    gr = gr < 0 ? 0 : (gr >= H_ ? H_ - 1 : gr);   // clamped; masked below
    const int4 v = *(const int4*)(lab + gr * W_);
    const unsigned e1x = (v.x == 1), e1y = (v.y == 1),
                   e1z = (v.z == 1), e1w = (v.w == 1);
    f0 |= (unsigned long long)(1u + e1x) << (2 * a);
    f1 |= (unsigned long long)(1u + e1y) << (2 * a);
    f2 |= (unsigned long long)(1u + e1z) << (2 * a);
    f3 |= (unsigned long long)(1u + e1w) << (2 * a);
    if (a >= R_ && a < R_ + TH_) {
      const int sh = 2 * (a - R_);
      cp0 |= (e1x | ((unsigned)(v.x == 255) << 1)) << sh;
      cp1 |= (e1y | ((unsigned)(v.y == 255) << 1)) << sh;
      cp2 |= (e1z | ((unsigned)(v.z == 255) << 1)) << sh;
      cp3 |= (e1w | ((unsigned)(v.w == 255) << 1)) << sh;
    }
  }
  // clip: OOB image rows / OOB lane columns contribute nothing
  {
    const int tv = gr0 == 0 ? R_ : 0;                   // invalid top rows
    const int hi = LH < (487 - gr0) ? LH : (487 - gr0); // first invalid bottom
    unsigned long long rm = ((1ull << (2 * (hi - tv))) - 1ull) << (2 * tv);
    if (!colinb) rm = 0;
    f0 &= rm; f1 &= rm; f2 &= rm; f3 &= rm;
  }

  // ---- phase 2: issue ALL logits loads (the one deliberate big live set:
  //      16 float4 = 64 VGPR); latency hides under phases 3-4 ----
  const bool outl = (lane >= 2) && (lane < 56);   // 54 lanes x 4 = 216 cols
  float4 g0[TH_], g1[TH_];
  if (outl) {
    const float* pg = lg + (size_t)gr0 * W_ + cb0;
#pragma unroll
    for (int o = 0; o < TH_; ++o) {
      g0[o] = *(const float4*)(pg + o * W_);
      g1[o] = *(const float4*)(pg + o * W_ + HW);
    }
  }

  // ---- phase 3: horizontal 15-OR, exact per column over 4-col lanes ----
  // col 4l+j window [4l+j-7, 4l+j+7]:
  //  j=0: sfx3(l-2)|all(l-1..l+1)
  //  j=1: sfx2(l-2)|core|pfx1(l+2)   j=2: sfx1(l-2)|core|pfx2(l+2)
  //  j=3:          all(l-1..l+1)|pfx3(l+2)
  // shuffle garbage only reaches lanes outside [2,56) -> never consumed.
  const unsigned long long allf = f0 | f1 | f2 | f3;
  const unsigned long long s2 = f2 | f3, s3 = f1 | s2;
  const unsigned long long p2 = f0 | f1, p3 = p2 | f2;
  const unsigned long long core =
      shfl_up64(allf, 1) | allf | shfl_dn64(allf, 1);
  unsigned long long w0 = core | shfl_up64(s3, 2);
  unsigned long long w1 = core | shfl_up64(s2, 2) | shfl_dn64(f0, 2);
  unsigned long long w2 = core | shfl_up64(f3, 2) | shfl_dn64(p2, 2);
  unsigned long long w3 = core | shfl_dn64(p3, 2);

  // ---- phase 4: vertical 15-OR (bit 2o = OR over label rows o..o+14) ----
  w0 |= w0 >> 2;  w0 |= w0 >> 4;  w0 |= w0 >> 8;  w0 |= w0 >> 14;
  w1 |= w1 >> 2;  w1 |= w1 >> 4;  w1 |= w1 >> 8;  w1 |= w1 >> 14;
  w2 |= w2 >> 2;  w2 |= w2 >> 4;  w2 |= w2 >> 8;  w2 |= w2 >> 14;
  w3 |= w3 >> 2;  w3 |= w3 >> 4;  w3 |= w3 >> 8;  w3 |= w3 >> 14;

  // ---- phase 5: select + accumulate ----
  double lsum = 0.0;
  unsigned lcnt = 0;
  if (outl) {
#pragma unroll
    for (int o = 0; o < TH_; ++o) {
      const unsigned b0 = (unsigned)(w0 >> (2 * o)) & 3u;
      const unsigned b1 = (unsigned)(w1 >> (2 * o)) & 3u;
      const unsigned b2 = (unsigned)(w2 >> (2 * o)) & 3u;
      const unsigned b3 = (unsigned)(w3 >> (2 * o)) & 3u;
      const unsigned q0 = (cp0 >> (2 * o)) & 3u;
      const unsigned q1 = (cp1 >> (2 * o)) & 3u;
      const unsigned q2 = (cp2 >> (2 * o)) & 3u;
      const unsigned q3 = (cp3 >> (2 * o)) & 3u;
      const float4 a = g0[o], c = g1[o];
      const bool k0 = (b0 == 3u) && !(q0 & 2u);
      const bool k1 = (b1 == 3u) && !(q1 & 2u);
      const bool k2 = (b2 == 3u) && !(q2 & 2u);
      const bool k3 = (b3 == 3u) && !(q3 & 2u);
      lsum += k0 ? (double)((q0 & 1u) ? c.x : a.x) : 0.0;
      lsum += k1 ? (double)((q1 & 1u) ? c.y : a.y) : 0.0;
      lsum += k2 ? (double)((q2 & 1u) ? c.z : a.z) : 0.0;
      lsum += k3 ? (double)((q3 & 1u) ? c.w : a.w) : 0.0;
      lcnt += (unsigned)k0 + k1 + k2 + k3;
    }
  }

  // ---- wave + block reduction -> one double2 per block ----
#pragma unroll
  for (int off = 32; off > 0; off >>= 1) {
    lsum += __shfl_down(lsum, off, 64);
    lcnt += __shfl_down(lcnt, off, 64);
  }
  if ((tid & 63) == 0) { red_s[wv] = lsum; red_c[wv] = lcnt; }
  __syncthreads();                            // tail-only
  if (tid == 0) {
    const double s = red_s[0] + red_s[1] + red_s[2] + red_s[3];
    const double c = (double)(red_c[0] + red_c[1] + red_c[2] + red_c[3]);
    partials[blockIdx.x] = make_double2(s, c);
  }
}

extern "C" __global__ __launch_bounds__(1024)
void boundary_loss_final(const double2* __restrict__ partials,
                         float* __restrict__ out)
{
  __shared__ double red_s[16];
  __shared__ double red_c[16];
  const int tid = threadIdx.x;
  double s = 0.0, c = 0.0;
  for (int i = tid; i < NBLKP; i += 1024) {
    const double2 p = partials[i];
    s += p.x;
    c += p.y;
  }
#pragma unroll
  for (int off = 32; off > 0; off >>= 1) {
    s += __shfl_down(s, off, 64);
    c += __shfl_down(c, off, 64);
  }
  const int wave = tid >> 6;
  if ((tid & 63) == 0) { red_s[wave] = s; red_c[wave] = c; }
  __syncthreads();
  if (tid == 0) {
    double ts = 0.0, tc = 0.0;
#pragma unroll
    for (int i = 0; i < 16; ++i) { ts += red_s[i]; tc += red_c[i]; }
    if (tc < 1.0) tc = 1.0;
    out[0] = (float)(-ts / tc);
  }
}

extern "C" void kernel_launch(void* const* d_in, const int* in_sizes, int n_in,
                              void* d_out, int out_size, void* d_ws, size_t ws_size,
                              hipStream_t stream)
{
  const float* logits = (const float*)d_in[0];
  const int* labels = (const int*)d_in[1];
  float* out = (float*)d_out;
  double2* partials = (double2*)d_ws;  // NBLKP*16 B = 30,720 B; every slot
                                       // written by main -> no init needed.

  boundary_loss_main<<<dim3(NBLKP), 256, 0, stream>>>(logits, labels, partials);
  boundary_loss_final<<<1, 1024, 0, stream>>>(partials, out);
}